// Round 5
// baseline (4156.473 us; speedup 1.0000x reference)
//
#include <hip/hip_runtime.h>
#include <math.h>

#define TT 50
#define MM 128
#define PP 128
#define FF 64
#define NB 4
#define NTHR 1024
#define BN_EPS 1e-5f

__device__ __forceinline__ float fsig(float x)  { return 1.0f / (1.0f + __expf(-x)); }
__device__ __forceinline__ float ftanh(float x) { return 1.0f - 2.0f / (__expf(2.0f * x) + 1.0f); }

__device__ __forceinline__ float dot4(float4 a, float4 b) {
    return a.x * b.x + a.y * b.y + a.z * b.z + a.w * b.w;
}

// R3/R4 lesson: hipcc's scheduler targets 8 waves/EU for this memory-heavy body
// regardless of __launch_bounds__, capping VGPR at 64 and spilling xp[] to
// scratch (FETCH 2.1 GB). Only 16 waves (4/EU) can ever be resident (LDS 126 KB
// -> 1 block/CU), so pin waves/EU to exactly 4: VGPR budget 128, no spill.
__global__ __launch_bounds__(NTHR)
__attribute__((amdgpu_waves_per_eu(4, 4)))
void decoder_kernel(
    const float* __restrict__ X,      // (B,T,M)
    const float* __restrict__ yprev,  // (B,T,F)
    const float* __restrict__ w1,     // (128,384)  [w1_d | w1_c | w1_x]
    const float* __restrict__ b1,
    const float* __restrict__ w2,     // (1,128)
    const float* __restrict__ b2,
    const float* __restrict__ fcw,    // (64,192)
    const float* __restrict__ fcb,
    const float* __restrict__ bng,
    const float* __restrict__ bnb,
    const float* __restrict__ bnm,
    const float* __restrict__ bnv,
    const float* __restrict__ wih0,   // (512,64)
    const float* __restrict__ whh0,   // (512,128)
    const float* __restrict__ bih0,
    const float* __restrict__ bhh0,
    const float* __restrict__ wih1,   // (512,128)
    const float* __restrict__ whh1,   // (512,128)
    const float* __restrict__ bih1,
    const float* __restrict__ bhh1,
    const float* __restrict__ fcfw,   // (64,256)
    const float* __restrict__ fcfb,
    float* __restrict__ out)          // (B,64)
{
    __shared__ __align__(16) float Xs[NB][TT][MM + 4];     // 105,600 B (pad 132)
    __shared__ __align__(16) float sp[NB][MM + 4];
    __shared__ __align__(16) float h0s[2][NB][PP + 4];
    __shared__ __align__(16) float h1s[2][NB][PP + 4];
    __shared__ __align__(16) float c0s[NB][PP + 4], c1s[NB][PP + 4];
    __shared__ __align__(16) float ctxs[NB][MM + 4];
    __shared__ __align__(16) float yts[NB][FF + 4], ytils[NB][FF + 4];
    __shared__ float scs[NB][68];
    __shared__ float w2s[MM];

    const int tid = threadIdx.x;
    const int b0 = blockIdx.x * NB;

    // ---- prologue: X tile -> LDS ----
    for (int i4 = tid; i4 < NB * TT * 32; i4 += NTHR) {
        int bb = i4 / (TT * 32);
        int r  = i4 % (TT * 32);
        float4 v = ((const float4*)(X + (size_t)(b0 + bb) * TT * MM))[r];
        *(float4*)&Xs[bb][r >> 5][(r & 31) * 4] = v;
    }
    for (int i = tid; i < NB * (PP + 4); i += NTHR) {
        int bb = i / (PP + 4), k = i % (PP + 4);
        h0s[0][bb][k] = 0.f; h0s[1][bb][k] = 0.f;
        h1s[0][bb][k] = 0.f; h1s[1][bb][k] = 0.f;
        c0s[bb][k] = 0.f;    c1s[bb][k] = 0.f;
    }
    if (tid < MM) w2s[tid] = w2[tid];
    __syncthreads();

    // ================= per-phase thread mappings (all ts-invariant) =================
    const int rowA = tid >> 3, bbA = (tid >> 1) & 3, halfA = tid & 1;
    const float b1v = b1[rowA];
    const int bq = tid >> 8, rr = tid & 255;
    const bool own = rr < 4 * TT;
    const int tq = rr >> 2, qq = rr & 3;
    const int bbD = tid >> 8, mD = (tid >> 1) & 127, thD = tid & 1;
    const int fE = tid >> 4, bbE = (tid >> 2) & 3, ksE = tid & 3;
    const float fck1 = rsqrtf(bnv[fE] + BN_EPS) * bng[fE];
    const float fck0 = (fcb[fE] - bnm[fE]) * fck1 + bnb[fE];
    const int kFG = tid >> 3, bbF = (tid >> 1) & 3, gh = tid & 1;
    const int r0 = gh * 2 * PP + kFG, r1 = gh * 2 * PP + PP + kFG;
    const float bF0a = bih0[r0] + bhh0[r0], bF0b = bih0[r1] + bhh0[r1];
    const float bF1a = bih1[r0] + bhh1[r0], bF1b = bih1[r1] + bhh1[r1];
    const float b2v = b2[0];

    // ---- x_proj in registers: owner (bq,tq,qq) holds xp[n], n = qq*32+0..31 ----
    float xp[32];
    #pragma unroll
    for (int n = 0; n < 32; ++n) xp[n] = 0.f;
    if (own) {
        for (int m4 = 0; m4 < 32; ++m4) {
            float4 xv = *(const float4*)&Xs[bq][tq][m4 * 4];
            #pragma unroll
            for (int n = 0; n < 32; ++n) {
                float4 w = *(const float4*)(w1 + (size_t)(qq * 32 + n) * 384 + 256 + m4 * 4);
                xp[n] += dot4(xv, w);
            }
        }
    }

    for (int ts = 0; ts < TT; ++ts) {
        const int p = ts & 1;

        // ---- A: state_proj (K-split over wd.h1 / wc.c1) ----
        {
            const float* wbase = w1 + (size_t)rowA * 384 + halfA * 128;
            const float* vec = halfA ? &c1s[bbA][0] : &h1s[p][bbA][0];
            float a = 0.f;
            #pragma unroll 8
            for (int k4 = 0; k4 < 32; ++k4) {
                float4 w = *(const float4*)(wbase + k4 * 4);
                float4 v = *(const float4*)(vec + k4 * 4);
                a += dot4(w, v);
            }
            a += __shfl_xor(a, 1);
            if (halfA == 0) sp[bbA][rowA] = a + b1v;
        }
        __syncthreads();

        // ---- B: score ----
        if (own) {
            float acc = 0.f;
            #pragma unroll
            for (int n = 0; n < 32; ++n)
                acc += ftanh(xp[n] + sp[bq][qq * 32 + n]) * w2s[qq * 32 + n];
            acc += __shfl_xor(acc, 1);
            acc += __shfl_xor(acc, 2);
            if (qq == 0) scs[bq][tq] = acc + b2v;
        }
        __syncthreads();

        // ---- C: softmax (4 waves) + y_t load ----
        if (tid < 256) {
            int b = tid >> 6, t = tid & 63;
            float v = (t < TT) ? scs[b][t] : -1e30f;
            float mx = v;
            #pragma unroll
            for (int o = 32; o; o >>= 1) mx = fmaxf(mx, __shfl_xor(mx, o));
            float e = (t < TT) ? __expf(v - mx) : 0.f;
            float s = e;
            #pragma unroll
            for (int o = 32; o; o >>= 1) s += __shfl_xor(s, o);
            if (t < TT) scs[b][t] = e / s;
        } else if (tid < 512) {
            int i = tid - 256; int bb = i >> 6, f = i & 63;
            yts[bb][f] = yprev[((size_t)(b0 + bb) * TT + ts) * FF + f];
        }
        __syncthreads();

        // ---- D: context (t-split halves) ----
        {
            float acc = 0.f;
            #pragma unroll
            for (int t = 0; t < 25; ++t) {
                int tt = thD * 25 + t;
                acc += scs[bbD][tt] * Xs[bbD][tt][mD];
            }
            acc += __shfl_xor(acc, 1);
            if (thD == 0) ctxs[bbD][mD] = acc;
        }
        __syncthreads();

        // ---- E: fc + batchnorm (K-split by 4) ----
        {
            const float* wr = fcw + (size_t)fE * 192;
            float acc = 0.f;
            #pragma unroll
            for (int j = 0; j < 8; ++j) {
                int k4 = ksE * 8 + j;
                float4 w = *(const float4*)(wr + k4 * 4);
                float4 cx = *(const float4*)&ctxs[bbE][k4 * 4];
                acc += dot4(w, cx);
            }
            #pragma unroll
            for (int j = 0; j < 4; ++j) {
                int k4 = ksE * 4 + j;
                float4 w = *(const float4*)(wr + 128 + k4 * 4);
                float4 yv = *(const float4*)&yts[bbE][k4 * 4];
                acc += dot4(w, yv);
            }
            acc += __shfl_xor(acc, 1);
            acc += __shfl_xor(acc, 2);
            if (ksE == 0) ytils[bbE][fE] = acc * fck1 + fck0;
        }
        __syncthreads();

        // ---- F: lstm0 (2 gate rows per thread) + update ----
        {
            float a0 = bF0a, a1 = bF0b;
            const float* wi0 = wih0 + (size_t)r0 * FF;
            const float* wi1 = wih0 + (size_t)r1 * FF;
            #pragma unroll 8
            for (int k4 = 0; k4 < 16; ++k4) {
                float4 x = *(const float4*)&ytils[bbF][k4 * 4];
                a0 += dot4(x, *(const float4*)(wi0 + k4 * 4));
                a1 += dot4(x, *(const float4*)(wi1 + k4 * 4));
            }
            const float* wh0 = whh0 + (size_t)r0 * PP;
            const float* wh1 = whh0 + (size_t)r1 * PP;
            #pragma unroll 8
            for (int k4 = 0; k4 < 32; ++k4) {
                float4 h = *(const float4*)&h0s[p][bbF][k4 * 4];
                a0 += dot4(h, *(const float4*)(wh0 + k4 * 4));
                a1 += dot4(h, *(const float4*)(wh1 + k4 * 4));
            }
            float og0 = __shfl_xor(a0, 1);   // partner's (g | i)
            float og1 = __shfl_xor(a1, 1);   // partner's (o | f)
            if (gh == 0) {
                float ii = fsig(a0), ff_ = fsig(a1), gg = ftanh(og0), oo = fsig(og1);
                float cn = ff_ * c0s[bbF][kFG] + ii * gg;
                c0s[bbF][kFG] = cn;
                h0s[p ^ 1][bbF][kFG] = oo * ftanh(cn);
            }
        }
        __syncthreads();

        // ---- G: lstm1 (2 gate rows per thread) + update ----
        {
            float a0 = bF1a, a1 = bF1b;
            const float* wi0 = wih1 + (size_t)r0 * PP;
            const float* wi1 = wih1 + (size_t)r1 * PP;
            const float* wh0 = whh1 + (size_t)r0 * PP;
            const float* wh1 = whh1 + (size_t)r1 * PP;
            #pragma unroll 8
            for (int k4 = 0; k4 < 32; ++k4) {
                float4 x = *(const float4*)&h0s[p ^ 1][bbF][k4 * 4];
                a0 += dot4(x, *(const float4*)(wi0 + k4 * 4));
                a1 += dot4(x, *(const float4*)(wi1 + k4 * 4));
            }
            #pragma unroll 8
            for (int k4 = 0; k4 < 32; ++k4) {
                float4 h = *(const float4*)&h1s[p][bbF][k4 * 4];
                a0 += dot4(h, *(const float4*)(wh0 + k4 * 4));
                a1 += dot4(h, *(const float4*)(wh1 + k4 * 4));
            }
            float og0 = __shfl_xor(a0, 1);
            float og1 = __shfl_xor(a1, 1);
            if (gh == 0) {
                float ii = fsig(a0), ff_ = fsig(a1), gg = ftanh(og0), oo = fsig(og1);
                float cn = ff_ * c1s[bbF][kFG] + ii * gg;
                c1s[bbF][kFG] = cn;
                h1s[p ^ 1][bbF][kFG] = oo * ftanh(cn);
            }
        }
        __syncthreads();
    }

    // ---- y_pred = relu([h1, ctx] @ fcf_w.T + fcf_b); final h1 in h1s[0] (TT even) ----
    {
        const float* wr = fcfw + (size_t)fE * 256;
        float acc = 0.f;
        #pragma unroll
        for (int j = 0; j < 16; ++j) {
            int k4 = ksE * 16 + j;
            float4 w = *(const float4*)(wr + k4 * 4);
            float4 v;
            if (k4 < 32) v = *(const float4*)&h1s[0][bbE][k4 * 4];
            else         v = *(const float4*)&ctxs[bbE][(k4 - 32) * 4];
            acc += dot4(w, v);
        }
        acc += __shfl_xor(acc, 1);
        acc += __shfl_xor(acc, 2);
        if (ksE == 0) out[(size_t)(b0 + bbE) * FF + fE] = fmaxf(acc + fcfb[fE], 0.f);
    }
}

extern "C" void kernel_launch(void* const* d_in, const int* in_sizes, int n_in,
                              void* d_out, int out_size, void* d_ws, size_t ws_size,
                              hipStream_t stream) {
    (void)in_sizes; (void)n_in; (void)d_ws; (void)ws_size; (void)out_size;
    const float* X    = (const float*)d_in[0];
    const float* yp   = (const float*)d_in[1];
    const float* w1   = (const float*)d_in[2];
    const float* b1   = (const float*)d_in[3];
    const float* w2   = (const float*)d_in[4];
    const float* b2   = (const float*)d_in[5];
    const float* fcw  = (const float*)d_in[6];
    const float* fcb  = (const float*)d_in[7];
    const float* bng  = (const float*)d_in[8];
    const float* bnb  = (const float*)d_in[9];
    const float* bnm  = (const float*)d_in[10];
    const float* bnv  = (const float*)d_in[11];
    const float* wih0 = (const float*)d_in[12];
    const float* whh0 = (const float*)d_in[13];
    const float* bih0 = (const float*)d_in[14];
    const float* bhh0 = (const float*)d_in[15];
    const float* wih1 = (const float*)d_in[16];
    const float* whh1 = (const float*)d_in[17];
    const float* bih1 = (const float*)d_in[18];
    const float* bhh1 = (const float*)d_in[19];
    const float* fcfw = (const float*)d_in[20];
    const float* fcfb = (const float*)d_in[21];
    float* out = (float*)d_out;

    decoder_kernel<<<dim3(1024 / NB), dim3(NTHR), 0, stream>>>(
        X, yp, w1, b1, w2, b2, fcw, fcb, bng, bnb, bnm, bnv,
        wih0, whh0, bih0, bhh0, wih1, whh1, bih1, bhh1, fcfw, fcfb, out);
}

// Round 6
// 1262.736 us; speedup vs baseline: 3.2916x; 3.2916x over previous
//
#include <hip/hip_runtime.h>
#include <math.h>

#define TT 50
#define MM 128
#define PP 128
#define FF 64
#define NB 4
#define NTHR 512
#define BN_EPS 1e-5f

typedef unsigned int   u32;
typedef unsigned short u16;
typedef _Float16 h2 __attribute__((ext_vector_type(2)));

__device__ __forceinline__ float fsig(float x)  { return 1.0f / (1.0f + __expf(-x)); }
__device__ __forceinline__ float ftanh(float x) { return 1.0f - 2.0f / (__expf(2.0f * x) + 1.0f); }

__device__ __forceinline__ u16 f2h(float x) { _Float16 h = (_Float16)x; u16 r; __builtin_memcpy(&r, &h, 2); return r; }
__device__ __forceinline__ float h2f(u16 u) { _Float16 h; __builtin_memcpy(&h, &u, 2); return (float)h; }

__device__ __forceinline__ float dot2(u32 a, u32 b, float c) {
#if __has_builtin(__builtin_amdgcn_fdot2)
    h2 ha, hb; __builtin_memcpy(&ha, &a, 4); __builtin_memcpy(&hb, &b, 4);
    return __builtin_amdgcn_fdot2(ha, hb, c, false);
#else
    return c + h2f((u16)(a & 0xffffu)) * h2f((u16)(b & 0xffffu))
             + h2f((u16)(a >> 16))     * h2f((u16)(b >> 16));
#endif
}
__device__ __forceinline__ float dot8(uint4 w, uint4 v, float acc) {
    acc = dot2(w.x, v.x, acc); acc = dot2(w.y, v.y, acc);
    acc = dot2(w.z, v.z, acc); acc = dot2(w.w, v.w, acc);
    return acc;
}

__global__ __launch_bounds__(256) void f2h_kernel(const float* __restrict__ s,
                                                  u16* __restrict__ d, int n) {
    int i = blockIdx.x * 256 + threadIdx.x;
    if (i < n) d[i] = f2h(s[i]);
}

// R2 structure (512 thr, NB=4, VGPR=128 known-good codegen), weights fp16+dot2.
__global__ __launch_bounds__(NTHR, 2) void decoder_kernel(
    const float* __restrict__ X,      // (B,T,M) fp32
    const float* __restrict__ yprev,  // (B,T,F) fp32
    const u16*   __restrict__ w1h,    // (128,384) fp16 [w1_d | w1_c | w1_x]
    const float* __restrict__ b1,
    const float* __restrict__ w2,
    const float* __restrict__ b2,
    const u16*   __restrict__ fcwh,   // (64,192) fp16
    const float* __restrict__ fcb,
    const float* __restrict__ bng,
    const float* __restrict__ bnb,
    const float* __restrict__ bnm,
    const float* __restrict__ bnv,
    const u16*   __restrict__ wih0h,  // (512,64) fp16
    const u16*   __restrict__ whh0h,  // (512,128) fp16
    const float* __restrict__ bih0,
    const float* __restrict__ bhh0,
    const u16*   __restrict__ wih1h,  // (512,128) fp16
    const u16*   __restrict__ whh1h,  // (512,128) fp16
    const float* __restrict__ bih1,
    const float* __restrict__ bhh1,
    const u16*   __restrict__ fcfwh,  // (64,256) fp16
    const float* __restrict__ fcfb,
    float* __restrict__ out)          // (B,64)
{
    __shared__ __align__(16) u16   Xh[NB][TT][MM + 8];     // 54.4 KB fp16 X
    __shared__ __align__(16) float sp[NB][MM + 4];
    __shared__ __align__(16) u16   h0h[2][NB][PP + 8];     // fp16 h (dot operand)
    __shared__ __align__(16) u16   h1h[2][NB][PP + 8];
    __shared__ __align__(16) u16   c1h[NB][PP + 8];        // fp16 c1 (phase-A dot)
    __shared__ __align__(16) float c0f[NB][PP + 4], c1f[NB][PP + 4]; // fp32 recurrence
    __shared__ __align__(16) u16   ctxh[NB][MM + 8];
    __shared__ __align__(16) u16   yth[NB][FF + 8], ytilh[NB][FF + 8];
    __shared__ float scs[NB][68];
    __shared__ float w2s[MM];

    const int tid = threadIdx.x;
    const int b0 = blockIdx.x * NB;

    // ---- prologue: X -> fp16 LDS ----
    for (int i4 = tid; i4 < NB * TT * 32; i4 += NTHR) {
        int bb = i4 / (TT * 32);
        int r  = i4 % (TT * 32);
        float4 v = ((const float4*)(X + (size_t)(b0 + bb) * TT * MM))[r];
        uint2 pk;
        pk.x = (u32)f2h(v.x) | ((u32)f2h(v.y) << 16);
        pk.y = (u32)f2h(v.z) | ((u32)f2h(v.w) << 16);
        *(uint2*)&Xh[bb][r >> 5][(r & 31) * 4] = pk;
    }
    for (int i = tid; i < NB * (PP + 8); i += NTHR) {
        int bb = i / (PP + 8), k = i % (PP + 8);
        h0h[0][bb][k] = 0; h0h[1][bb][k] = 0;
        h1h[0][bb][k] = 0; h1h[1][bb][k] = 0;
        c1h[bb][k] = 0;
        if (k < PP + 4) { c0f[bb][k] = 0.f; c1f[bb][k] = 0.f; }
    }
    if (tid < MM) w2s[tid] = w2[tid];
    __syncthreads();

    // ---- per-phase mappings (R2) ----
    const int nq = tid >> 2, bbq = tid & 3;                 // A/F/G: row, batch
    const float b1v = b1[nq];
    const int bq = tid >> 7, rr = tid & 127;                // B: batch, sub
    const bool own = rr < 2 * TT;
    const int tq = rr >> 1, qq = rr & 1;
    const float b2v = b2[0];
    const float bi0 = bih0[nq] + bhh0[nq];
    const float bf0 = bih0[PP + nq] + bhh0[PP + nq];
    const float bg0 = bih0[2 * PP + nq] + bhh0[2 * PP + nq];
    const float bo0 = bih0[3 * PP + nq] + bhh0[3 * PP + nq];
    const float bi1 = bih1[nq] + bhh1[nq];
    const float bf1 = bih1[PP + nq] + bhh1[PP + nq];
    const float bg1 = bih1[2 * PP + nq] + bhh1[2 * PP + nq];
    const float bo1 = bih1[3 * PP + nq] + bhh1[3 * PP + nq];
    float fck1 = 0.f, fck0 = 0.f;
    if (tid < 256) {
        int f = tid >> 2;
        fck1 = rsqrtf(bnv[f] + BN_EPS) * bng[f];
        fck0 = (fcb[f] - bnm[f]) * fck1 + bnb[f];
    }

    // ---- x_proj in registers: owner (bq,tq,qq) holds xp[n], n = qq*64+0..63 ----
    float xp[64];
    #pragma unroll
    for (int n = 0; n < 64; ++n) xp[n] = 0.f;
    if (own) {
        for (int m8 = 0; m8 < 16; ++m8) {
            uint4 xv = *(const uint4*)&Xh[bq][tq][m8 * 8];
            #pragma unroll
            for (int n = 0; n < 64; ++n) {
                uint4 wv = *(const uint4*)(w1h + (size_t)(qq * 64 + n) * 384 + 256 + m8 * 8);
                xp[n] = dot8(wv, xv, xp[n]);
            }
        }
    }

    for (int ts = 0; ts < TT; ++ts) {
        const int p = ts & 1;

        // ---- A: state_proj[bb][n] = w1_d[n,:].h1 + w1_c[n,:].c1 + b1 ----
        {
            const u16* wd = w1h + (size_t)nq * 384;
            float acc = b1v;
            #pragma unroll 4
            for (int k8 = 0; k8 < 16; ++k8) {
                uint4 wv = *(const uint4*)(wd + k8 * 8);
                uint4 hv = *(const uint4*)&h1h[p][bbq][k8 * 8];
                acc = dot8(wv, hv, acc);
                uint4 wc = *(const uint4*)(wd + 128 + k8 * 8);
                uint4 cv = *(const uint4*)&c1h[bbq][k8 * 8];
                acc = dot8(wc, cv, acc);
            }
            sp[bbq][nq] = acc;
        }
        __syncthreads();

        // ---- B: score[t] = sum_n tanh(xp + sp) * w2 ----
        if (own) {
            float acc = 0.f;
            #pragma unroll
            for (int n = 0; n < 64; ++n)
                acc += ftanh(xp[n] + sp[bq][qq * 64 + n]) * w2s[qq * 64 + n];
            acc += __shfl_xor(acc, 1);
            if (qq == 0) scs[bq][tq] = acc + b2v;
        }
        __syncthreads();

        // ---- C: softmax over 50 + y_t load (fp16) ----
        if (tid < 256) {
            int b = tid >> 6, t = tid & 63;
            float v = (t < TT) ? scs[b][t] : -1e30f;
            float mx = v;
            #pragma unroll
            for (int o = 32; o; o >>= 1) mx = fmaxf(mx, __shfl_xor(mx, o));
            float e = (t < TT) ? __expf(v - mx) : 0.f;
            float s = e;
            #pragma unroll
            for (int o = 32; o; o >>= 1) s += __shfl_xor(s, o);
            if (t < TT) scs[b][t] = e / s;
        } else {
            int i = tid - 256; int bb = i >> 6, f = i & 63;
            yth[bb][f] = f2h(yprev[((size_t)(b0 + bb) * TT + ts) * FF + f]);
        }
        __syncthreads();

        // ---- D: context[m] = sum_t beta[t]*X[t][m] (fp32 acc, fp16 out) ----
        {
            int b = tid >> 7, m = tid & 127;
            float acc = 0.f;
            #pragma unroll
            for (int t = 0; t < TT; ++t) acc += scs[b][t] * h2f(Xh[b][t][m]);
            ctxh[b][m] = f2h(acc);
        }
        __syncthreads();

        // ---- E: fc + batchnorm ----
        if (tid < 256) {
            int f = tid >> 2, bb = tid & 3;
            const u16* wr = fcwh + (size_t)f * 192;
            float acc = 0.f;
            #pragma unroll 4
            for (int k8 = 0; k8 < 16; ++k8) {
                uint4 w = *(const uint4*)(wr + k8 * 8);
                uint4 cv = *(const uint4*)&ctxh[bb][k8 * 8];
                acc = dot8(w, cv, acc);
            }
            #pragma unroll 4
            for (int k8 = 0; k8 < 8; ++k8) {
                uint4 w = *(const uint4*)(wr + 128 + k8 * 8);
                uint4 yv = *(const uint4*)&yth[bb][k8 * 8];
                acc = dot8(w, yv, acc);
            }
            ytilh[bb][f] = f2h(acc * fck1 + fck0);
        }
        __syncthreads();

        // ---- F: lstm0 (4 gate rows per thread) + update ----
        {
            const int k = nq, bb = bbq;
            float ai = bi0, af = bf0, ag = bg0, ao = bo0;
            #pragma unroll 2
            for (int k8 = 0; k8 < 8; ++k8) {
                uint4 xv = *(const uint4*)&ytilh[bb][k8 * 8];
                ai = dot8(*(const uint4*)(wih0h + (size_t)k * 64 + k8 * 8), xv, ai);
                af = dot8(*(const uint4*)(wih0h + (size_t)(PP + k) * 64 + k8 * 8), xv, af);
                ag = dot8(*(const uint4*)(wih0h + (size_t)(2 * PP + k) * 64 + k8 * 8), xv, ag);
                ao = dot8(*(const uint4*)(wih0h + (size_t)(3 * PP + k) * 64 + k8 * 8), xv, ao);
            }
            #pragma unroll 2
            for (int k8 = 0; k8 < 16; ++k8) {
                uint4 hv = *(const uint4*)&h0h[p][bb][k8 * 8];
                ai = dot8(*(const uint4*)(whh0h + (size_t)k * 128 + k8 * 8), hv, ai);
                af = dot8(*(const uint4*)(whh0h + (size_t)(PP + k) * 128 + k8 * 8), hv, af);
                ag = dot8(*(const uint4*)(whh0h + (size_t)(2 * PP + k) * 128 + k8 * 8), hv, ag);
                ao = dot8(*(const uint4*)(whh0h + (size_t)(3 * PP + k) * 128 + k8 * 8), hv, ao);
            }
            float ii = fsig(ai), fg = fsig(af), gg = ftanh(ag), oo = fsig(ao);
            float cn = fg * c0f[bb][k] + ii * gg;
            c0f[bb][k] = cn;
            h0h[p ^ 1][bb][k] = f2h(oo * ftanh(cn));
        }
        __syncthreads();

        // ---- G: lstm1 + update ----
        {
            const int k = nq, bb = bbq;
            float ai = bi1, af = bf1, ag = bg1, ao = bo1;
            #pragma unroll 2
            for (int k8 = 0; k8 < 16; ++k8) {
                uint4 xv = *(const uint4*)&h0h[p ^ 1][bb][k8 * 8];
                ai = dot8(*(const uint4*)(wih1h + (size_t)k * 128 + k8 * 8), xv, ai);
                af = dot8(*(const uint4*)(wih1h + (size_t)(PP + k) * 128 + k8 * 8), xv, af);
                ag = dot8(*(const uint4*)(wih1h + (size_t)(2 * PP + k) * 128 + k8 * 8), xv, ag);
                ao = dot8(*(const uint4*)(wih1h + (size_t)(3 * PP + k) * 128 + k8 * 8), xv, ao);
            }
            #pragma unroll 2
            for (int k8 = 0; k8 < 16; ++k8) {
                uint4 hv = *(const uint4*)&h1h[p][bb][k8 * 8];
                ai = dot8(*(const uint4*)(whh1h + (size_t)k * 128 + k8 * 8), hv, ai);
                af = dot8(*(const uint4*)(whh1h + (size_t)(PP + k) * 128 + k8 * 8), hv, af);
                ag = dot8(*(const uint4*)(whh1h + (size_t)(2 * PP + k) * 128 + k8 * 8), hv, ag);
                ao = dot8(*(const uint4*)(whh1h + (size_t)(3 * PP + k) * 128 + k8 * 8), hv, ao);
            }
            float ii = fsig(ai), fg = fsig(af), gg = ftanh(ag), oo = fsig(ao);
            float cn = fg * c1f[bb][k] + ii * gg;
            c1f[bb][k] = cn;
            c1h[bb][k] = f2h(cn);
            h1h[p ^ 1][bb][k] = f2h(oo * ftanh(cn));
        }
        __syncthreads();
    }

    // ---- y_pred = relu([h1, ctx] @ fcf_w.T + fcf_b); final h1 in side 0 (TT even) ----
    if (tid < 256) {
        int f = tid >> 2, bb = tid & 3;
        const u16* wr = fcfwh + (size_t)f * 256;
        float acc = fcfb[f];
        #pragma unroll 4
        for (int k8 = 0; k8 < 16; ++k8) {
            uint4 w = *(const uint4*)(wr + k8 * 8);
            uint4 hv = *(const uint4*)&h1h[0][bb][k8 * 8];
            acc = dot8(w, hv, acc);
        }
        #pragma unroll 4
        for (int k8 = 0; k8 < 16; ++k8) {
            uint4 w = *(const uint4*)(wr + 128 + k8 * 8);
            uint4 cv = *(const uint4*)&ctxh[bb][k8 * 8];
            acc = dot8(w, cv, acc);
        }
        out[(size_t)(b0 + bb) * FF + f] = fmaxf(acc, 0.f);
    }
}

extern "C" void kernel_launch(void* const* d_in, const int* in_sizes, int n_in,
                              void* d_out, int out_size, void* d_ws, size_t ws_size,
                              hipStream_t stream) {
    (void)in_sizes; (void)n_in; (void)out_size; (void)ws_size;
    const float* X    = (const float*)d_in[0];
    const float* yp   = (const float*)d_in[1];
    const float* w1   = (const float*)d_in[2];
    const float* b1   = (const float*)d_in[3];
    const float* w2   = (const float*)d_in[4];
    const float* b2   = (const float*)d_in[5];
    const float* fcw  = (const float*)d_in[6];
    const float* fcb  = (const float*)d_in[7];
    const float* bng  = (const float*)d_in[8];
    const float* bnb  = (const float*)d_in[9];
    const float* bnm  = (const float*)d_in[10];
    const float* bnv  = (const float*)d_in[11];
    const float* wih0 = (const float*)d_in[12];
    const float* whh0 = (const float*)d_in[13];
    const float* bih0 = (const float*)d_in[14];
    const float* bhh0 = (const float*)d_in[15];
    const float* wih1 = (const float*)d_in[16];
    const float* whh1 = (const float*)d_in[17];
    const float* bih1 = (const float*)d_in[18];
    const float* bhh1 = (const float*)d_in[19];
    const float* fcfw = (const float*)d_in[20];
    const float* fcfb = (const float*)d_in[21];
    float* out = (float*)d_out;

    // fp16 weight cache in d_ws (rewritten every call; deterministic)
    u16* wsh    = (u16*)d_ws;
    u16* w1h    = wsh;                 // 128*384 = 49152
    u16* fcwh   = w1h + 49152;         // 64*192  = 12288
    u16* wih0h  = fcwh + 12288;        // 512*64  = 32768
    u16* whh0h  = wih0h + 32768;       // 512*128 = 65536
    u16* wih1h  = whh0h + 65536;       // 65536
    u16* whh1h  = wih1h + 65536;       // 65536
    u16* fcfwh  = whh1h + 65536;       // 64*256 = 16384  (total 307200 u16 = 614.4 KB)

    f2h_kernel<<<dim3((49152 + 255) / 256), dim3(256), 0, stream>>>(w1, w1h, 49152);
    f2h_kernel<<<dim3((12288 + 255) / 256), dim3(256), 0, stream>>>(fcw, fcwh, 12288);
    f2h_kernel<<<dim3((32768 + 255) / 256), dim3(256), 0, stream>>>(wih0, wih0h, 32768);
    f2h_kernel<<<dim3((65536 + 255) / 256), dim3(256), 0, stream>>>(whh0, whh0h, 65536);
    f2h_kernel<<<dim3((65536 + 255) / 256), dim3(256), 0, stream>>>(wih1, wih1h, 65536);
    f2h_kernel<<<dim3((65536 + 255) / 256), dim3(256), 0, stream>>>(whh1, whh1h, 65536);
    f2h_kernel<<<dim3((16384 + 255) / 256), dim3(256), 0, stream>>>(fcfw, fcfwh, 16384);

    decoder_kernel<<<dim3(1024 / NB), dim3(NTHR), 0, stream>>>(
        X, yp, w1h, b1, w2, b2, fcwh, fcb, bng, bnb, bnm, bnv,
        wih0h, whh0h, bih0, bhh0, wih1h, whh1h, bih1, bhh1, fcfwh, fcfb, out);
}